// Round 5
// baseline (3879.595 us; speedup 1.0000x reference)
//
#include <hip/hip_runtime.h>
#include <stdint.h>

typedef unsigned int u32;
typedef unsigned short u16;
typedef unsigned long long u64;
typedef __attribute__((ext_vector_type(8))) short short8;
typedef __attribute__((ext_vector_type(4))) float f32x4;

#define NB 64
#define NS 512
#define NI 512
#define NH 1024

// ---- workspace byte offsets ----
#define OFF_AT    0ULL          // inputs transposed->bf16, swizzled: [32768][512] bf16
#define OFF_H     0ULL          // h image, 2 buffers [64][1024] bf16 (aliases AT; init runs after xproj)
#define OFF_WI    33554432ULL   // input weights bf16 swizzled: [3][1024][512]
#define OFF_WH    36700160ULL   // recurrent weights, MFMA B-frag order: [3][64][32][64][8]
#define OFF_XR    42991616ULL   // xr [512 s][1024 h][64 b] bf16 (transposed pack)
#define OFF_XZ    110100480ULL  // xz
#define OFF_XN    177209344ULL  // xn
#define OFF_FLAGS 244318208ULL  // 64 WG-flags (64B stride); 8 per-XCD claim ctrs @ +16384

__device__ __forceinline__ u16 f2bf(float f){
  u32 u = __float_as_uint(f);
  u += 0x7fffu + ((u >> 16) & 1u);
  return (u16)(u >> 16);
}
__device__ __forceinline__ float bf2f(u16 h){
  return __uint_as_float(((u32)h) << 16);
}
__device__ __forceinline__ float sigm(float x){ return 1.0f / (1.0f + __expf(-x)); }
__device__ __forceinline__ float tanhf_(float x){
  float a = fabsf(x);
  float e = __expf(-2.0f * a);
  float t = (1.0f - e) / (1.0f + e);
  return copysignf(t, x);
}
__device__ __forceinline__ void gl_lds16(const void* g, void* l){
  __builtin_amdgcn_global_load_lds((const __attribute__((address_space(1))) void*)g,
                                   (__attribute__((address_space(3))) void*)l, 16, 0, 0);
}
__device__ __forceinline__ uint4 pack8(float4 a, float4 b){
  uint4 o;
  o.x = (u32)f2bf(a.x) | ((u32)f2bf(a.y) << 16);
  o.y = (u32)f2bf(a.z) | ((u32)f2bf(a.w) << 16);
  o.z = (u32)f2bf(b.x) | ((u32)f2bf(b.y) << 16);
  o.w = (u32)f2bf(b.z) | ((u32)f2bf(b.w) << 16);
  return o;
}

// ---- pinned-cache-behavior asm ops ----
// MALL-point poll load: bypasses L1 AND L2; embedded wait makes data valid.
__device__ __forceinline__ u32 ld4_mall(const u32* p){
  u32 r;
  asm volatile("global_load_dword %0, %1, off sc0 sc1\n\ts_waitcnt vmcnt(0)"
               : "=v"(r) : "v"(p) : "memory");
  return r;
}
// MALL-point flag store (write-through past L2) -- fire and forget.
__device__ __forceinline__ void st4_mall(u32* p, u32 v){
  asm volatile("global_store_dword %0, %1, off sc0 sc1" :: "v"(p), "v"(v) : "memory");
}
// h staging, steady state: L1-bypass (sc0), L2-allocating (NO nt: keep h
// lines MRU-resident -- next step's publish write-hits them).
__device__ __forceinline__ u64 ld8_l2(const void* p){
  u64 r;
  asm volatile("global_load_dwordx2 %0, %1, off sc0" : "=v"(r) : "v"(p));
  return r;
}
// h staging, step 0 (replay-safe): MALL point.
__device__ __forceinline__ u64 ld8_mall(const void* p){
  u64 r;
  asm volatile("global_load_dwordx2 %0, %1, off sc0 sc1" : "=v"(r) : "v"(p));
  return r;
}
// x stream load: non-temporal (evict-first) -> does NOT displace the h
// working set from the XCD L2. THIS is the round-5 fix.
__device__ __forceinline__ u64 ld8_nt(const void* p){
  u64 r;
  asm volatile("global_load_dwordx2 %0, %1, off nt" : "=v"(r) : "v"(p));
  return r;
}
// out stream store: non-temporal -> no write-allocate thrash of the L2.
__device__ __forceinline__ void st4_nt(void* p, float v){
  asm volatile("global_store_dword %0, %1, off nt" :: "v"(p), "v"(v) : "memory");
}

// ---------------- prep kernels ----------------

// inputs [b][s][i] f32 -> AT [m=s*64+b][i] bf16, per-row 16B-block XOR swizzle
__global__ void GRU_prep_at(const float* __restrict__ in, u16* __restrict__ at){
  int idx = blockIdx.x * 256 + threadIdx.x;      // 2,097,152 total
  int m = idx >> 6, k8 = idx & 63;
  int s = m >> 6, b = m & 63;
  const float* src = in + (((size_t)b * NS + s) * NI + k8 * 8);
  float4 f0 = *(const float4*)(src);
  float4 f1 = *(const float4*)(src + 4);
  uint4 o = pack8(f0, f1);
  *(uint4*)((char*)at + (size_t)m * 1024 + ((k8 * 16) ^ ((m & 7) << 4))) = o;
}

// w_i{r,z,n} [h][i] f32 -> WI [g][h][i] bf16 swizzled
__global__ void GRU_prep_wi(const float* __restrict__ w0, const float* __restrict__ w1,
                            const float* __restrict__ w2, u16* __restrict__ wi){
  int idx = blockIdx.x * 256 + threadIdx.x;      // 196,608 total
  int g = idx >> 16;
  int rem = idx & 65535;
  int h = rem >> 6, k8 = rem & 63;
  const float* wsrc = (g == 0) ? w0 : ((g == 1) ? w1 : w2);
  const float* src = wsrc + (size_t)h * NI + k8 * 8;
  float4 f0 = *(const float4*)(src);
  float4 f1 = *(const float4*)(src + 4);
  uint4 o = pack8(f0, f1);
  *(uint4*)((char*)wi + ((size_t)(g * NH + h)) * 1024 + ((k8 * 16) ^ ((h & 7) << 4))) = o;
}

// w_h{r,z,n} [f][k] f32 -> WH in MFMA B-fragment order: [g][ftile(64)][kc(32)][lane(64)][8 bf16]
__global__ void GRU_prep_wh(const float* __restrict__ w0, const float* __restrict__ w1,
                            const float* __restrict__ w2, u16* __restrict__ wh){
  int idx = blockIdx.x * 256 + threadIdx.x;      // 393,216 total
  int l = idx & 63;
  int kc = (idx >> 6) & 31;
  int t = idx >> 11;            // g*64 + ftile
  int g = t >> 6, ft = t & 63;
  const float* wsrc = (g == 0) ? w0 : ((g == 1) ? w1 : w2);
  int f = ft * 16 + (l & 15);
  int k = kc * 32 + ((l >> 4) * 8);
  const float* src = wsrc + (size_t)f * NH + k;
  float4 f0 = *(const float4*)(src);
  float4 f1 = *(const float4*)(src + 4);
  uint4 o = pack8(f0, f1);
  *(uint4*)((char*)wh + (size_t)idx * 16) = o;
}

// hidden[0] f32 -> h buffer 0 (bf16, LINEAR [64][1024]); zero flags + claim ctrs.
// Launched AFTER GRU_xproj (h image aliases the AT region).
__global__ void GRU_init_h(const float* __restrict__ h0, u16* __restrict__ hImg,
                           u32* __restrict__ flags){
  int gt = blockIdx.x * 256 + threadIdx.x;       // 8192 threads
  if (gt < 8192){
    int b = gt >> 7, k8 = gt & 127;
    const float* src = h0 + (size_t)b * NH + k8 * 8;
    float4 f0 = *(const float4*)(src);
    float4 f1 = *(const float4*)(src + 4);
    uint4 o = pack8(f0, f1);
    *(uint4*)((char*)hImg + (size_t)b * 2048 + k8 * 16) = o;
  }
  if (gt < 256) flags[gt * 16] = 0;              // 64 WG flags (+ spare), 64B stride
  if (gt >= 256 && gt < 264) flags[4096 + (gt - 256) * 16] = 0;  // 8 claim ctrs
}

// ---------------- input-projection GEMM (unchanged, proven) ----------------
__global__ __launch_bounds__(256) void GRU_xproj(const u16* __restrict__ AT,
    const u16* __restrict__ WI,
    const float* __restrict__ bi0, const float* __restrict__ bi1, const float* __restrict__ bi2,
    u16* __restrict__ xr, u16* __restrict__ xz, u16* __restrict__ xn){
  __shared__ __align__(16) char lds[32768];
  int tid = threadIdx.x;
  int l = tid & 63, w = tid >> 6;
  int c = l & 15, q = l >> 4;
  int mt = blockIdx.x, nt = blockIdx.y, g = blockIdx.z;
  const float* bi = (g == 0) ? bi0 : ((g == 1) ? bi1 : bi2);
  u16* xg = (g == 0) ? xr : ((g == 1) ? xz : xn);
  int m0 = mt * 128, n0 = nt * 128;
  int wm = w >> 1, wn = w & 1;

  f32x4 acc[4][4];
  #pragma unroll
  for (int i = 0; i < 4; ++i)
    #pragma unroll
    for (int j = 0; j < 4; ++j) acc[i][j] = (f32x4)0.0f;

  const char* Asrc = (const char*)AT + (size_t)m0 * 1024;
  const char* Bsrc = (const char*)WI + ((size_t)g * NH + n0) * 1024;

  for (int kt = 0; kt < 8; ++kt){
    #pragma unroll
    for (int r2 = 0; r2 < 4; ++r2){
      int idx = r2 * 256 + tid;
      int row = idx >> 3, k8 = idx & 7;
      gl_lds16(Asrc + (size_t)row * 1024 + kt * 128 + k8 * 16, lds + ((idx >> 6) << 10));
    }
    #pragma unroll
    for (int r2 = 0; r2 < 4; ++r2){
      int idx = r2 * 256 + tid;
      int row = idx >> 3, k8 = idx & 7;
      gl_lds16(Bsrc + (size_t)row * 1024 + kt * 128 + k8 * 16, lds + 16384 + ((idx >> 6) << 10));
    }
    __syncthreads();
    #pragma unroll
    for (int kk = 0; kk < 2; ++kk){
      short8 af[4], bf[4];
      int kb = kk * 64 + q * 16;
      #pragma unroll
      for (int mf = 0; mf < 4; ++mf){
        int row = wm * 64 + mf * 16 + c;
        af[mf] = *(const short8*)(lds + row * 128 + (kb ^ ((row & 7) << 4)));
      }
      #pragma unroll
      for (int nf = 0; nf < 4; ++nf){
        int row = wn * 64 + nf * 16 + c;
        bf[nf] = *(const short8*)(lds + 16384 + row * 128 + (kb ^ ((row & 7) << 4)));
      }
      #pragma unroll
      for (int mf = 0; mf < 4; ++mf)
        #pragma unroll
        for (int nf = 0; nf < 4; ++nf)
          acc[mf][nf] = __builtin_amdgcn_mfma_f32_16x16x32_bf16(af[mf], bf[nf], acc[mf][nf], 0, 0, 0);
    }
    __syncthreads();
  }
  int sidx = mt * 2 + wm;
  #pragma unroll
  for (int nf = 0; nf < 4; ++nf){
    int n = n0 + wn * 64 + nf * 16 + c;
    float bv = bi[n];
    #pragma unroll
    for (int mf = 0; mf < 4; ++mf){
      int b0 = mf * 16 + q * 4;
      u32 w0 = (u32)f2bf(acc[mf][nf][0] + bv) | ((u32)f2bf(acc[mf][nf][1] + bv) << 16);
      u32 w1 = (u32)f2bf(acc[mf][nf][2] + bv) | ((u32)f2bf(acc[mf][nf][3] + bv) << 16);
      uint2 o; o.x = w0; o.y = w1;
      *(uint2*)(xg + ((size_t)sidx * NH + n) * NB + b0) = o;
    }
  }
}

// ---------------- persistent recurrent kernel ----------------
// Round-4 structure (PROVEN correct): MALL flags + XCD-pinned bg groups with
// local-L2 h exchange. Round-5 fix: the x stream (nt loads) and out stream
// (nt stores) no longer allocate aggressively in L2, so the 64KB/XCD h
// working set stays resident -> publish = L2-hit ack, staging = L2 hit.
__global__ __launch_bounds__(256, 1) void GRU_rec(const u16* __restrict__ WH,
    const u16* __restrict__ xr, const u16* __restrict__ xz, const u16* __restrict__ xn,
    const float* __restrict__ bhr, const float* __restrict__ bhz, const float* __restrict__ bhn,
    const float* __restrict__ h0, u16* __restrict__ hImg, u32* __restrict__ flags,
    float* __restrict__ out){
  // [0,32K) staging; [32K,34K) transpose tile; +ctrl. Oversized (82KB) to pin 1 WG/CU.
  __shared__ __align__(16) char hl[83968];

  // HW_REG_XCC_ID: id=20, offset=0, size=4 -> simm16 = ((4-1)<<11)|20 = 6164
  u32 xcd = (u32)__builtin_amdgcn_s_getreg(6164);
  if (xcd >= 4) return;                      // only XCDs 0..3 carry bg groups

  int tid = threadIdx.x;
  int* roleS = (int*)(hl + 34816);
  if (tid == 0)
    *roleS = (int)__hip_atomic_fetch_add(flags + 4096 + xcd * 16, 1u,
                                         __ATOMIC_RELAXED, __HIP_MEMORY_SCOPE_AGENT);
  __syncthreads();
  int role = *roleS;
  if (role >= 16) return;                    // surplus same-XCD WGs exit

  int bg = (int)xcd, fg = role;              // 16 batches x 64 features per WG
  int l = tid & 63, w = tid >> 6;
  int c = l & 15, q = l >> 4;

  // weights -> registers: bw[gate][kc]  (384 regs, AGPR-backed)
  short8 bw[3][32];
  {
    const short8* base = (const short8*)WH;
    int ft = fg * 4 + w;
    #pragma unroll
    for (int g = 0; g < 3; ++g)
      #pragma unroll
      for (int kc = 0; kc < 32; ++kc)
        bw[g][kc] = base[(size_t)((g * 64 + ft) * 32 + kc) * 64 + l];
  }

  int frow = fg * 64 + w * 16 + c;           // this lane's feature
  int brow = bg * 16 + q * 4;                // this lane's first batch row
  float vbhr = bhr[frow], vbhz = bhz[frow], vbhn = bhn[frow];

  float hprev[4];
  #pragma unroll
  for (int j = 0; j < 4; ++j) hprev[j] = h0[(size_t)(brow + j) * NH + frow];

  char* hbytes = (char*)hImg;
  int r = tid >> 4, ci = tid & 15;           // staging coords
  u32* myflag = flags + (size_t)(bg * 16 + fg) * 16;
  u32* pollp  = flags + (size_t)(bg * 16 + (l & 15)) * 16;

  for (int s = 0; s < NS; ++s){
    // x loads (independent of h): nt stream, issued before the poll so their
    // HBM latency hides under the flag-detect; values valid after the staging
    // vmcnt(0)+sched_barrier below, consumed only after __syncthreads.
    u64 xrv, xzv, xnv;
    {
      size_t xo = ((size_t)s * NH + frow) * NB + brow;
      xrv = ld8_nt(xr + xo);
      xzv = ld8_nt(xz + xo);
      xnv = ld8_nt(xn + xo);
    }
    if (s > 0){
      // MALL-point poll of the 16 producer-WG flags (bounded: fail-fast)
      for (int it = 0; it < 4096; ++it){
        u32 v = ld4_mall(pollp);
        if (__all((int)(v >= (u32)s))) break;
      }
      __builtin_amdgcn_sched_barrier(0);
    }

    // stage h slice (rows bg*16..+16 of buffer s&1): local-L2 loads (step 0: MALL)
    {
      const char* hsrc = hbytes + (size_t)(s & 1) * 131072
                         + (size_t)(bg * 16 + r) * 2048 + ci * 8;
      u64 hv[16];
      if (s == 0){
        #pragma unroll
        for (int e = 0; e < 16; ++e) hv[e] = ld8_mall(hsrc + e * 128);
      } else {
        #pragma unroll
        for (int e = 0; e < 16; ++e) hv[e] = ld8_l2(hsrc + e * 128);
      }
      // raw asm loads carry no data-dep: wait, then pin ordering for all
      // consumers (incl. the x values) with a full sched barrier
      asm volatile("s_waitcnt vmcnt(0)" ::: "memory");
      __builtin_amdgcn_sched_barrier(0);
      char* dst = hl + r * 2048;
      #pragma unroll
      for (int e = 0; e < 16; ++e)
        *(u64*)(dst + ((e * 128 + ci * 8) ^ ((r & 7) << 4))) = hv[e];
    }
    __syncthreads();

    // MFMA: acc[b16][f16] per gate, K=1024, even/odd chains
    f32x4 ar0 = (f32x4)0.0f, ar1 = (f32x4)0.0f;
    f32x4 az0 = (f32x4)0.0f, az1 = (f32x4)0.0f;
    f32x4 an0 = (f32x4)0.0f, an1 = (f32x4)0.0f;
    #pragma unroll
    for (int kc = 0; kc < 32; kc += 2){
      short8 a0 = *(const short8*)(hl + c * 2048 + ((kc * 64 + q * 16) ^ ((c & 7) << 4)));
      short8 a1 = *(const short8*)(hl + c * 2048 + (((kc + 1) * 64 + q * 16) ^ ((c & 7) << 4)));
      ar0 = __builtin_amdgcn_mfma_f32_16x16x32_bf16(a0, bw[0][kc], ar0, 0, 0, 0);
      az0 = __builtin_amdgcn_mfma_f32_16x16x32_bf16(a0, bw[1][kc], az0, 0, 0, 0);
      an0 = __builtin_amdgcn_mfma_f32_16x16x32_bf16(a0, bw[2][kc], an0, 0, 0, 0);
      ar1 = __builtin_amdgcn_mfma_f32_16x16x32_bf16(a1, bw[0][kc + 1], ar1, 0, 0, 0);
      az1 = __builtin_amdgcn_mfma_f32_16x16x32_bf16(a1, bw[1][kc + 1], az1, 0, 0, 0);
      an1 = __builtin_amdgcn_mfma_f32_16x16x32_bf16(a1, bw[2][kc + 1], an1, 0, 0, 0);
    }
    f32x4 ar = ar0 + ar1, az = az0 + az1, an = an0 + an1;

    // combine; h state carried in f32 regs; write LDS transpose tile
    float hn4[4];
    #pragma unroll
    for (int j = 0; j < 4; ++j){
      float rv = sigm(ar[j] + bf2f((u16)(xrv >> (16 * j))) + vbhr);
      float zv = sigm(az[j] + bf2f((u16)(xzv >> (16 * j))) + vbhz);
      float nv = tanhf_(bf2f((u16)(xnv >> (16 * j))) + rv * (an[j] + vbhn));
      float hn = (1.0f - zv) * nv + zv * hprev[j];
      hprev[j] = hn;
      hn4[j] = hn;
      *(u16*)(hl + 32768 + (q * 4 + j) * 128 + (w * 16 + c) * 2) = f2bf(hn);
    }
    __syncthreads();
    // publish h tile: one 8B PLAIN store per thread (L2-hit, fast ack --
    // the wave coalescer merges 16 lanes into one full 128B line per row)
    {
      u64 tv = *(const u64*)(hl + 32768 + r * 128 + ci * 8);
      *(u64*)(hbytes + (size_t)((s + 1) & 1) * 131072
              + (size_t)(bg * 16 + r) * 2048 + (size_t)(fg * 16 + ci) * 8) = tv;
    }
    // drain publish (L2 ack only: x consumed, outs not yet issued)
    asm volatile("s_waitcnt vmcnt(0)" ::: "memory");
    __syncthreads();
    if (tid == 0) st4_mall(myflag, (u32)(s + 1));
    // out stores AFTER the flag: nt stream, off the signal path; their acks
    // complete during the next step's poll-detect window
    #pragma unroll
    for (int j = 0; j < 4; ++j)
      st4_nt(out + ((size_t)(brow + j) * NS + s) * NH + frow, hn4[j]);
  }

  // final hidden state
  #pragma unroll
  for (int j = 0; j < 4; ++j)
    st4_nt(out + (size_t)NB * NS * NH + (size_t)(brow + j) * NH + frow, hprev[j]);
  asm volatile("s_waitcnt vmcnt(0)" ::: "memory");
}

// ---------------- launcher ----------------
extern "C" void kernel_launch(void* const* d_in, const int* in_sizes, int n_in,
                              void* d_out, int out_size, void* d_ws, size_t ws_size,
                              hipStream_t stream){
  const float* inputs = (const float*)d_in[0];
  const float* hidden = (const float*)d_in[1];
  const float* w_ir = (const float*)d_in[2];
  const float* w_iz = (const float*)d_in[3];
  const float* w_in = (const float*)d_in[4];
  const float* b_ir = (const float*)d_in[5];
  const float* b_iz = (const float*)d_in[6];
  const float* b_in = (const float*)d_in[7];
  const float* w_hr = (const float*)d_in[8];
  const float* w_hz = (const float*)d_in[9];
  const float* w_hn = (const float*)d_in[10];
  const float* b_hr = (const float*)d_in[11];
  const float* b_hz = (const float*)d_in[12];
  const float* b_hn = (const float*)d_in[13];

  char* ws = (char*)d_ws;
  u16* AT = (u16*)(ws + OFF_AT);
  u16* WI = (u16*)(ws + OFF_WI);
  u16* WH = (u16*)(ws + OFF_WH);
  u16* XR = (u16*)(ws + OFF_XR);
  u16* XZ = (u16*)(ws + OFF_XZ);
  u16* XN = (u16*)(ws + OFF_XN);
  u16* HIMG = (u16*)(ws + OFF_H);
  u32* FLAGS = (u32*)(ws + OFF_FLAGS);
  float* out = (float*)d_out;

  GRU_prep_at<<<dim3(8192), dim3(256), 0, stream>>>(inputs, AT);
  GRU_prep_wi<<<dim3(768), dim3(256), 0, stream>>>(w_ir, w_iz, w_in, WI);
  GRU_prep_wh<<<dim3(1536), dim3(256), 0, stream>>>(w_hr, w_hz, w_hn, WH);
  GRU_xproj<<<dim3(256, 8, 3), dim3(256), 0, stream>>>(AT, WI, b_ir, b_iz, b_in, XR, XZ, XN);
  GRU_init_h<<<dim3(32), dim3(256), 0, stream>>>(hidden, HIMG, FLAGS);  // after xproj: HIMG aliases AT
  GRU_rec<<<dim3(1024), dim3(256), 0, stream>>>(WH, XR, XZ, XN, b_hr, b_hz, b_hn,
                                                hidden, HIMG, FLAGS, out);
}

// Round 7
// 2784.779 us; speedup vs baseline: 1.3931x; 1.3931x over previous
//
#include <hip/hip_runtime.h>
#include <stdint.h>

typedef unsigned int u32;
typedef unsigned short u16;
typedef unsigned long long u64;
typedef __attribute__((ext_vector_type(8))) short short8;
typedef __attribute__((ext_vector_type(4))) float f32x4;

#define NB 64
#define NS 512
#define NI 512
#define NH 1024

// ---- workspace byte offsets (round-0 layout: H has its own region) ----
#define OFF_AT    0ULL          // inputs transposed->bf16, swizzled: [32768][512] bf16
#define OFF_WI    33554432ULL   // input weights bf16 swizzled: [3][1024][512]
#define OFF_WH    36700160ULL   // recurrent weights, MFMA B-frag order: [3][64][32][64][8]
#define OFF_XR    42991616ULL   // xr [512 s][1024 h][64 b] bf16 (transposed pack)
#define OFF_XZ    110100480ULL  // xz
#define OFF_XN    177209344ULL  // xn
#define OFF_H     244318208ULL  // h bf16 image, 2 buffers [64][1024] LINEAR
#define OFF_FLAGS 244580352ULL  // 4 per-bg step counters (64B stride)

__device__ __forceinline__ u16 f2bf(float f){
  u32 u = __float_as_uint(f);
  u += 0x7fffu + ((u >> 16) & 1u);
  return (u16)(u >> 16);
}
__device__ __forceinline__ float bf2f(u16 h){
  return __uint_as_float(((u32)h) << 16);
}
__device__ __forceinline__ float sigm(float x){ return 1.0f / (1.0f + __expf(-x)); }
__device__ __forceinline__ float tanhf_(float x){
  float a = fabsf(x);
  float e = __expf(-2.0f * a);
  float t = (1.0f - e) / (1.0f + e);
  return copysignf(t, x);
}
__device__ __forceinline__ void gl_lds16(const void* g, void* l){
  __builtin_amdgcn_global_load_lds((const __attribute__((address_space(1))) void*)g,
                                   (__attribute__((address_space(3))) void*)l, 16, 0, 0);
}
__device__ __forceinline__ uint4 pack8(float4 a, float4 b){
  uint4 o;
  o.x = (u32)f2bf(a.x) | ((u32)f2bf(a.y) << 16);
  o.y = (u32)f2bf(a.z) | ((u32)f2bf(a.w) << 16);
  o.z = (u32)f2bf(b.x) | ((u32)f2bf(b.y) << 16);
  o.w = (u32)f2bf(b.z) | ((u32)f2bf(b.w) << 16);
  return o;
}
// MALL-coherent (agent-scope) atomics -- the PROVEN round-0 primitives
__device__ __forceinline__ u64 ald8(const u64* p){
  return __hip_atomic_load(p, __ATOMIC_RELAXED, __HIP_MEMORY_SCOPE_AGENT);
}
__device__ __forceinline__ void ast8(u64* p, u64 v){
  __hip_atomic_store(p, v, __ATOMIC_RELAXED, __HIP_MEMORY_SCOPE_AGENT);
}

// ---------------- prep kernels (round-0 verbatim) ----------------

// inputs [b][s][i] f32 -> AT [m=s*64+b][i] bf16, per-row 16B-block XOR swizzle
__global__ void GRU_prep_at(const float* __restrict__ in, u16* __restrict__ at){
  int idx = blockIdx.x * 256 + threadIdx.x;      // 2,097,152 total
  int m = idx >> 6, k8 = idx & 63;
  int s = m >> 6, b = m & 63;
  const float* src = in + (((size_t)b * NS + s) * NI + k8 * 8);
  float4 f0 = *(const float4*)(src);
  float4 f1 = *(const float4*)(src + 4);
  uint4 o = pack8(f0, f1);
  *(uint4*)((char*)at + (size_t)m * 1024 + ((k8 * 16) ^ ((m & 7) << 4))) = o;
}

// w_i{r,z,n} [h][i] f32 -> WI [g][h][i] bf16 swizzled
__global__ void GRU_prep_wi(const float* __restrict__ w0, const float* __restrict__ w1,
                            const float* __restrict__ w2, u16* __restrict__ wi){
  int idx = blockIdx.x * 256 + threadIdx.x;      // 196,608 total
  int g = idx >> 16;
  int rem = idx & 65535;
  int h = rem >> 6, k8 = rem & 63;
  const float* wsrc = (g == 0) ? w0 : ((g == 1) ? w1 : w2);
  const float* src = wsrc + (size_t)h * NI + k8 * 8;
  float4 f0 = *(const float4*)(src);
  float4 f1 = *(const float4*)(src + 4);
  uint4 o = pack8(f0, f1);
  *(uint4*)((char*)wi + ((size_t)(g * NH + h)) * 1024 + ((k8 * 16) ^ ((h & 7) << 4))) = o;
}

// w_h{r,z,n} [f][k] f32 -> WH in MFMA B-fragment order: [g][ftile(64)][kc(32)][lane(64)][8 bf16]
__global__ void GRU_prep_wh(const float* __restrict__ w0, const float* __restrict__ w1,
                            const float* __restrict__ w2, u16* __restrict__ wh){
  int idx = blockIdx.x * 256 + threadIdx.x;      // 393,216 total
  int l = idx & 63;
  int kc = (idx >> 6) & 31;
  int t = idx >> 11;            // g*64 + ftile
  int g = t >> 6, ft = t & 63;
  const float* wsrc = (g == 0) ? w0 : ((g == 1) ? w1 : w2);
  int f = ft * 16 + (l & 15);
  int k = kc * 32 + ((l >> 4) * 8);
  const float* src = wsrc + (size_t)f * NH + k;
  float4 f0 = *(const float4*)(src);
  float4 f1 = *(const float4*)(src + 4);
  uint4 o = pack8(f0, f1);
  *(uint4*)((char*)wh + (size_t)idx * 16) = o;
}

// hidden[0] f32 -> h bf16 image buffer 0 (LINEAR [64][1024]); zero counters
__global__ void GRU_init_h(const float* __restrict__ h0, u16* __restrict__ hImg,
                           u32* __restrict__ flags){
  int gt = blockIdx.x * 256 + threadIdx.x;       // 8192 for h
  if (gt < 8192){
    int b = gt >> 7, k8 = gt & 127;
    const float* src = h0 + (size_t)b * NH + k8 * 8;
    float4 f0 = *(const float4*)(src);
    float4 f1 = *(const float4*)(src + 4);
    uint4 o = pack8(f0, f1);
    *(uint4*)((char*)hImg + (size_t)b * 2048 + k8 * 16) = o;
  }
  if (gt < 64) flags[gt * 16] = 0;               // counters live in lines 0..3
}

// ---------------- input-projection GEMM (round-0 verbatim) ----------------
__global__ __launch_bounds__(256) void GRU_xproj(const u16* __restrict__ AT,
    const u16* __restrict__ WI,
    const float* __restrict__ bi0, const float* __restrict__ bi1, const float* __restrict__ bi2,
    u16* __restrict__ xr, u16* __restrict__ xz, u16* __restrict__ xn){
  __shared__ __align__(16) char lds[32768];     // A: [0,16K), B: [16K,32K)
  int tid = threadIdx.x;
  int l = tid & 63, w = tid >> 6;
  int c = l & 15, q = l >> 4;
  int mt = blockIdx.x, nt = blockIdx.y, g = blockIdx.z;
  const float* bi = (g == 0) ? bi0 : ((g == 1) ? bi1 : bi2);
  u16* xg = (g == 0) ? xr : ((g == 1) ? xz : xn);
  int m0 = mt * 128, n0 = nt * 128;
  int wm = w >> 1, wn = w & 1;

  f32x4 acc[4][4];
  #pragma unroll
  for (int i = 0; i < 4; ++i)
    #pragma unroll
    for (int j = 0; j < 4; ++j) acc[i][j] = (f32x4)0.0f;

  const char* Asrc = (const char*)AT + (size_t)m0 * 1024;
  const char* Bsrc = (const char*)WI + ((size_t)g * NH + n0) * 1024;

  for (int kt = 0; kt < 8; ++kt){
    #pragma unroll
    for (int r2 = 0; r2 < 4; ++r2){
      int idx = r2 * 256 + tid;
      int row = idx >> 3, k8 = idx & 7;
      gl_lds16(Asrc + (size_t)row * 1024 + kt * 128 + k8 * 16, lds + ((idx >> 6) << 10));
    }
    #pragma unroll
    for (int r2 = 0; r2 < 4; ++r2){
      int idx = r2 * 256 + tid;
      int row = idx >> 3, k8 = idx & 7;
      gl_lds16(Bsrc + (size_t)row * 1024 + kt * 128 + k8 * 16, lds + 16384 + ((idx >> 6) << 10));
    }
    __syncthreads();
    #pragma unroll
    for (int kk = 0; kk < 2; ++kk){
      short8 af[4], bf[4];
      int kb = kk * 64 + q * 16;
      #pragma unroll
      for (int mf = 0; mf < 4; ++mf){
        int row = wm * 64 + mf * 16 + c;
        af[mf] = *(const short8*)(lds + row * 128 + (kb ^ ((row & 7) << 4)));
      }
      #pragma unroll
      for (int nf = 0; nf < 4; ++nf){
        int row = wn * 64 + nf * 16 + c;
        bf[nf] = *(const short8*)(lds + 16384 + row * 128 + (kb ^ ((row & 7) << 4)));
      }
      #pragma unroll
      for (int mf = 0; mf < 4; ++mf)
        #pragma unroll
        for (int nf = 0; nf < 4; ++nf)
          acc[mf][nf] = __builtin_amdgcn_mfma_f32_16x16x32_bf16(af[mf], bf[nf], acc[mf][nf], 0, 0, 0);
    }
    __syncthreads();
  }
  // epilogue: add bias, cvt bf16, store TRANSPOSED [s][n][b], 8B per (mf,nf)
  int sidx = mt * 2 + wm;             // row>>6 (mf*16+q*4+j <= 63)
  #pragma unroll
  for (int nf = 0; nf < 4; ++nf){
    int n = n0 + wn * 64 + nf * 16 + c;
    float bv = bi[n];
    #pragma unroll
    for (int mf = 0; mf < 4; ++mf){
      int b0 = mf * 16 + q * 4;       // batch of j=0
      u32 w0 = (u32)f2bf(acc[mf][nf][0] + bv) | ((u32)f2bf(acc[mf][nf][1] + bv) << 16);
      u32 w1 = (u32)f2bf(acc[mf][nf][2] + bv) | ((u32)f2bf(acc[mf][nf][3] + bv) << 16);
      uint2 o; o.x = w0; o.y = w1;
      *(uint2*)(xg + ((size_t)sidx * NH + n) * NB + b0) = o;
    }
  }
}

// ---------------- persistent recurrent kernel ----------------
// Round-0's PROVEN all-MALL protocol, WG-tile publish with the barrier-
// separated (TBAA-safe) LDS transpose. Two audited deltas only:
//  (1) out stores AFTER the counter post -> publish drain no longer waits
//      on out-store HBM acks (they retire under next step's staging waits);
//  (2) 16 per-WG flag lines -> ONE per-bg aggregated counter (tid0
//      fetch_add; consumers poll a single uniform-address line for 16*s).
__global__ __launch_bounds__(256, 1) void GRU_rec(const u16* __restrict__ WH,
    const u16* __restrict__ xr, const u16* __restrict__ xz, const u16* __restrict__ xn,
    const float* __restrict__ bhr, const float* __restrict__ bhz, const float* __restrict__ bhn,
    const float* __restrict__ h0, u16* __restrict__ hImg, u32* __restrict__ flags,
    float* __restrict__ out){
  __shared__ __align__(16) char hl[34816];      // [16 rows][2048B] swizzled + 2KB tile @32768
  int tid = threadIdx.x;
  int l = tid & 63, w = tid >> 6;
  int wg = blockIdx.x;
  int bg = wg >> 4, fg = wg & 15;
  int c = l & 15, q = l >> 4;

  // weights -> registers: bw[gate][kc]  (384 regs, AGPR-backed)
  short8 bw[3][32];
  {
    const short8* base = (const short8*)WH;
    int ft = fg * 4 + w;
    #pragma unroll
    for (int g = 0; g < 3; ++g)
      #pragma unroll
      for (int kc = 0; kc < 32; ++kc)
        bw[g][kc] = base[(size_t)((g * 64 + ft) * 32 + kc) * 64 + l];
  }

  int frow = fg * 64 + w * 16 + c;              // this lane's feature
  int brow = bg * 16 + q * 4;                   // this lane's first batch row
  float vbhr = bhr[frow], vbhz = bhz[frow], vbhn = bhn[frow];

  float hprev[4];
  #pragma unroll
  for (int j = 0; j < 4; ++j) hprev[j] = h0[(size_t)(brow + j) * NH + frow];

  char* hbytes = (char*)hImg;
  u32* ctr = flags + (size_t)bg * 16;           // ONE 64B counter line per bg
  int r = tid >> 4, ci = tid & 15;              // staging coords

  for (int s = 0; s < NS; ++s){
    // x loads (independent of h) issued before the poll to hide HBM latency
    u64 xrv, xzv, xnv;
    {
      size_t xo = ((size_t)s * NH + frow) * NB + brow;
      xrv = *(const u64*)(xr + xo);
      xzv = *(const u64*)(xz + xo);
      xnv = *(const u64*)(xn + xo);
    }
    if (s > 0){
      // single-line aggregated poll: ctr >= 16*s <=> all 16 WGs posted s-1
      u32 tgt = (u32)(16 * s);
      for (int it = 0; it < (1 << 20); ++it){   // bounded: fail-fast, never hang
        u32 v = __hip_atomic_load(ctr, __ATOMIC_RELAXED, __HIP_MEMORY_SCOPE_AGENT);
        if (v >= tgt) break;
      }
      __builtin_amdgcn_sched_barrier(0);
      asm volatile("" ::: "memory");
    }
    // stage h slice (rows bg*16..+16 of buffer s&1) via MALL-coherent loads
    {
      const u64* hsrc = (const u64*)(hbytes + (size_t)(s & 1) * 131072)
                        + (size_t)(bg * 16 + r) * 256 + ci;
      u64 hv[16];
      #pragma unroll
      for (int e = 0; e < 16; ++e) hv[e] = ald8(hsrc + e * 16);
      char* dst = hl + r * 2048;
      #pragma unroll
      for (int e = 0; e < 16; ++e)
        *(u64*)(dst + ((e * 128 + ci * 8) ^ ((r & 7) << 4))) = hv[e];
    }
    __syncthreads();

    // MFMA: acc[b16][f16] per gate, K=1024, even/odd chains
    f32x4 ar0 = (f32x4)0.0f, ar1 = (f32x4)0.0f;
    f32x4 az0 = (f32x4)0.0f, az1 = (f32x4)0.0f;
    f32x4 an0 = (f32x4)0.0f, an1 = (f32x4)0.0f;
    #pragma unroll
    for (int kc = 0; kc < 32; kc += 2){
      short8 a0 = *(const short8*)(hl + c * 2048 + ((kc * 64 + q * 16) ^ ((c & 7) << 4)));
      short8 a1 = *(const short8*)(hl + c * 2048 + (((kc + 1) * 64 + q * 16) ^ ((c & 7) << 4)));
      ar0 = __builtin_amdgcn_mfma_f32_16x16x32_bf16(a0, bw[0][kc], ar0, 0, 0, 0);
      az0 = __builtin_amdgcn_mfma_f32_16x16x32_bf16(a0, bw[1][kc], az0, 0, 0, 0);
      an0 = __builtin_amdgcn_mfma_f32_16x16x32_bf16(a0, bw[2][kc], an0, 0, 0, 0);
      ar1 = __builtin_amdgcn_mfma_f32_16x16x32_bf16(a1, bw[0][kc + 1], ar1, 0, 0, 0);
      az1 = __builtin_amdgcn_mfma_f32_16x16x32_bf16(a1, bw[1][kc + 1], az1, 0, 0, 0);
      an1 = __builtin_amdgcn_mfma_f32_16x16x32_bf16(a1, bw[2][kc + 1], an1, 0, 0, 0);
    }
    f32x4 ar = ar0 + ar1, az = az0 + az1, an = an0 + an1;

    // combine; h state carried in f32 regs; write LDS transpose tile
    float hn4[4];
    #pragma unroll
    for (int j = 0; j < 4; ++j){
      float rv = sigm(ar[j] + bf2f((u16)(xrv >> (16 * j))) + vbhr);
      float zv = sigm(az[j] + bf2f((u16)(xzv >> (16 * j))) + vbhz);
      float nv = tanhf_(bf2f((u16)(xnv >> (16 * j))) + rv * (an[j] + vbhn));
      float hn = (1.0f - zv) * nv + zv * hprev[j];
      hprev[j] = hn;
      hn4[j] = hn;
      *(u16*)(hl + 32768 + (q * 4 + j) * 128 + (w * 16 + c) * 2) = f2bf(hn);
    }
    __syncthreads();   // full barrier: makes the u16->u64 tile repack TBAA-safe
    // publish h tile: one 8B MALL store per thread, then ack-drain, then post
    {
      u64 tv = *(const u64*)(hl + 32768 + r * 128 + ci * 8);
      u64* hdst = (u64*)(hbytes + (size_t)((s + 1) & 1) * 131072)
                  + (size_t)(bg * 16 + r) * 256 + fg * 16 + ci;
      ast8(hdst, tv);
    }
    asm volatile("s_waitcnt vmcnt(0)" ::: "memory");
    __syncthreads();
    if (tid == 0)
      (void)__hip_atomic_fetch_add(ctr, 1u, __ATOMIC_RELAXED, __HIP_MEMORY_SCOPE_AGENT);
    // out stores AFTER the post: off the producer->consumer signal path;
    // their HBM acks retire under the next step's staging waits
    #pragma unroll
    for (int j = 0; j < 4; ++j)
      out[((size_t)(brow + j) * NS + s) * NH + frow] = hn4[j];
  }
  // final hidden state
  #pragma unroll
  for (int j = 0; j < 4; ++j)
    out[(size_t)NB * NS * NH + (size_t)(brow + j) * NH + frow] = hprev[j];
}

// ---------------- launcher (round-0 order: init before xproj) ----------------
extern "C" void kernel_launch(void* const* d_in, const int* in_sizes, int n_in,
                              void* d_out, int out_size, void* d_ws, size_t ws_size,
                              hipStream_t stream){
  const float* inputs = (const float*)d_in[0];
  const float* hidden = (const float*)d_in[1];
  const float* w_ir = (const float*)d_in[2];
  const float* w_iz = (const float*)d_in[3];
  const float* w_in = (const float*)d_in[4];
  const float* b_ir = (const float*)d_in[5];
  const float* b_iz = (const float*)d_in[6];
  const float* b_in = (const float*)d_in[7];
  const float* w_hr = (const float*)d_in[8];
  const float* w_hz = (const float*)d_in[9];
  const float* w_hn = (const float*)d_in[10];
  const float* b_hr = (const float*)d_in[11];
  const float* b_hz = (const float*)d_in[12];
  const float* b_hn = (const float*)d_in[13];

  char* ws = (char*)d_ws;
  u16* AT = (u16*)(ws + OFF_AT);
  u16* WI = (u16*)(ws + OFF_WI);
  u16* WH = (u16*)(ws + OFF_WH);
  u16* XR = (u16*)(ws + OFF_XR);
  u16* XZ = (u16*)(ws + OFF_XZ);
  u16* XN = (u16*)(ws + OFF_XN);
  u16* HIMG = (u16*)(ws + OFF_H);
  u32* FLAGS = (u32*)(ws + OFF_FLAGS);
  float* out = (float*)d_out;

  GRU_prep_at<<<dim3(8192), dim3(256), 0, stream>>>(inputs, AT);
  GRU_prep_wi<<<dim3(768), dim3(256), 0, stream>>>(w_ir, w_iz, w_in, WI);
  GRU_prep_wh<<<dim3(1536), dim3(256), 0, stream>>>(w_hr, w_hz, w_hn, WH);
  GRU_init_h<<<dim3(32), dim3(256), 0, stream>>>(hidden, HIMG, FLAGS);
  GRU_xproj<<<dim3(256, 8, 3), dim3(256), 0, stream>>>(AT, WI, b_ir, b_iz, b_in, XR, XZ, XN);
  GRU_rec<<<dim3(64), dim3(256), 0, stream>>>(WH, XR, XZ, XN, b_hr, b_hz, b_hn,
                                              hidden, HIMG, FLAGS, out);
}

// Round 8
// 2611.421 us; speedup vs baseline: 1.4856x; 1.0664x over previous
//
#include <hip/hip_runtime.h>
#include <stdint.h>

typedef unsigned int u32;
typedef unsigned short u16;
typedef unsigned long long u64;
typedef __attribute__((ext_vector_type(8))) short short8;
typedef __attribute__((ext_vector_type(4))) float f32x4;

#define NB 64
#define NS 512
#define NI 512
#define NH 1024

// ---- workspace byte offsets (round-0 layout) ----
#define OFF_AT    0ULL          // inputs transposed->bf16, swizzled: [32768][512] bf16
#define OFF_WI    33554432ULL   // input weights bf16 swizzled: [3][1024][512]
#define OFF_WH    36700160ULL   // recurrent weights, MFMA B-frag order: [3][64][32][64][8]
#define OFF_XR    42991616ULL   // xr [512 s][1024 h][64 b] bf16 (transposed pack)
#define OFF_XZ    110100480ULL  // xz
#define OFF_XN    177209344ULL  // xn
#define OFF_H     244318208ULL  // h bf16 image, 2 buffers [64][1024] LINEAR
#define OFF_FLAGS 244580352ULL  // 64 per-WG flags, 64B stride

__device__ __forceinline__ u16 f2bf(float f){
  u32 u = __float_as_uint(f);
  u += 0x7fffu + ((u >> 16) & 1u);
  return (u16)(u >> 16);
}
__device__ __forceinline__ float bf2f(u16 h){
  return __uint_as_float(((u32)h) << 16);
}
__device__ __forceinline__ float sigm(float x){ return 1.0f / (1.0f + __expf(-x)); }
__device__ __forceinline__ float tanhf_(float x){
  float a = fabsf(x);
  float e = __expf(-2.0f * a);
  float t = (1.0f - e) / (1.0f + e);
  return copysignf(t, x);
}
__device__ __forceinline__ void gl_lds16(const void* g, void* l){
  __builtin_amdgcn_global_load_lds((const __attribute__((address_space(1))) void*)g,
                                   (__attribute__((address_space(3))) void*)l, 16, 0, 0);
}
__device__ __forceinline__ uint4 pack8(float4 a, float4 b){
  uint4 o;
  o.x = (u32)f2bf(a.x) | ((u32)f2bf(a.y) << 16);
  o.y = (u32)f2bf(a.z) | ((u32)f2bf(a.w) << 16);
  o.z = (u32)f2bf(b.x) | ((u32)f2bf(b.y) << 16);
  o.w = (u32)f2bf(b.z) | ((u32)f2bf(b.w) << 16);
  return o;
}
// MALL-coherent (agent-scope) atomics -- the PROVEN round-0 primitives
__device__ __forceinline__ u64 ald8(const u64* p){
  return __hip_atomic_load(p, __ATOMIC_RELAXED, __HIP_MEMORY_SCOPE_AGENT);
}
__device__ __forceinline__ void ast8(u64* p, u64 v){
  __hip_atomic_store(p, v, __ATOMIC_RELAXED, __HIP_MEMORY_SCOPE_AGENT);
}

// ---------------- prep kernels (round-0 verbatim) ----------------

// inputs [b][s][i] f32 -> AT [m=s*64+b][i] bf16, per-row 16B-block XOR swizzle
__global__ void GRU_prep_at(const float* __restrict__ in, u16* __restrict__ at){
  int idx = blockIdx.x * 256 + threadIdx.x;      // 2,097,152 total
  int m = idx >> 6, k8 = idx & 63;
  int s = m >> 6, b = m & 63;
  const float* src = in + (((size_t)b * NS + s) * NI + k8 * 8);
  float4 f0 = *(const float4*)(src);
  float4 f1 = *(const float4*)(src + 4);
  uint4 o = pack8(f0, f1);
  *(uint4*)((char*)at + (size_t)m * 1024 + ((k8 * 16) ^ ((m & 7) << 4))) = o;
}

// w_i{r,z,n} [h][i] f32 -> WI [g][h][i] bf16 swizzled
__global__ void GRU_prep_wi(const float* __restrict__ w0, const float* __restrict__ w1,
                            const float* __restrict__ w2, u16* __restrict__ wi){
  int idx = blockIdx.x * 256 + threadIdx.x;      // 196,608 total
  int g = idx >> 16;
  int rem = idx & 65535;
  int h = rem >> 6, k8 = rem & 63;
  const float* wsrc = (g == 0) ? w0 : ((g == 1) ? w1 : w2);
  const float* src = wsrc + (size_t)h * NI + k8 * 8;
  float4 f0 = *(const float4*)(src);
  float4 f1 = *(const float4*)(src + 4);
  uint4 o = pack8(f0, f1);
  *(uint4*)((char*)wi + ((size_t)(g * NH + h)) * 1024 + ((k8 * 16) ^ ((h & 7) << 4))) = o;
}

// w_h{r,z,n} [f][k] f32 -> WH in MFMA B-fragment order: [g][ftile(64)][kc(32)][lane(64)][8 bf16]
__global__ void GRU_prep_wh(const float* __restrict__ w0, const float* __restrict__ w1,
                            const float* __restrict__ w2, u16* __restrict__ wh){
  int idx = blockIdx.x * 256 + threadIdx.x;      // 393,216 total
  int l = idx & 63;
  int kc = (idx >> 6) & 31;
  int t = idx >> 11;            // g*64 + ftile
  int g = t >> 6, ft = t & 63;
  const float* wsrc = (g == 0) ? w0 : ((g == 1) ? w1 : w2);
  int f = ft * 16 + (l & 15);
  int k = kc * 32 + ((l >> 4) * 8);
  const float* src = wsrc + (size_t)f * NH + k;
  float4 f0 = *(const float4*)(src);
  float4 f1 = *(const float4*)(src + 4);
  uint4 o = pack8(f0, f1);
  *(uint4*)((char*)wh + (size_t)idx * 16) = o;
}

// hidden[0] f32 -> h bf16 image buffer 0 (LINEAR [64][1024]); zero 64 flags
__global__ void GRU_init_h(const float* __restrict__ h0, u16* __restrict__ hImg,
                           u32* __restrict__ flags){
  int gt = blockIdx.x * 256 + threadIdx.x;       // 8192 for h
  if (gt < 8192){
    int b = gt >> 7, k8 = gt & 127;
    const float* src = h0 + (size_t)b * NH + k8 * 8;
    float4 f0 = *(const float4*)(src);
    float4 f1 = *(const float4*)(src + 4);
    uint4 o = pack8(f0, f1);
    *(uint4*)((char*)hImg + (size_t)b * 2048 + k8 * 16) = o;
  }
  if (gt < 64) flags[gt * 16] = 0;
}

// ---------------- input-projection GEMM (round-0 verbatim) ----------------
__global__ __launch_bounds__(256) void GRU_xproj(const u16* __restrict__ AT,
    const u16* __restrict__ WI,
    const float* __restrict__ bi0, const float* __restrict__ bi1, const float* __restrict__ bi2,
    u16* __restrict__ xr, u16* __restrict__ xz, u16* __restrict__ xn){
  __shared__ __align__(16) char lds[32768];     // A: [0,16K), B: [16K,32K)
  int tid = threadIdx.x;
  int l = tid & 63, w = tid >> 6;
  int c = l & 15, q = l >> 4;
  int mt = blockIdx.x, nt = blockIdx.y, g = blockIdx.z;
  const float* bi = (g == 0) ? bi0 : ((g == 1) ? bi1 : bi2);
  u16* xg = (g == 0) ? xr : ((g == 1) ? xz : xn);
  int m0 = mt * 128, n0 = nt * 128;
  int wm = w >> 1, wn = w & 1;

  f32x4 acc[4][4];
  #pragma unroll
  for (int i = 0; i < 4; ++i)
    #pragma unroll
    for (int j = 0; j < 4; ++j) acc[i][j] = (f32x4)0.0f;

  const char* Asrc = (const char*)AT + (size_t)m0 * 1024;
  const char* Bsrc = (const char*)WI + ((size_t)g * NH + n0) * 1024;

  for (int kt = 0; kt < 8; ++kt){
    #pragma unroll
    for (int r2 = 0; r2 < 4; ++r2){
      int idx = r2 * 256 + tid;
      int row = idx >> 3, k8 = idx & 7;
      gl_lds16(Asrc + (size_t)row * 1024 + kt * 128 + k8 * 16, lds + ((idx >> 6) << 10));
    }
    #pragma unroll
    for (int r2 = 0; r2 < 4; ++r2){
      int idx = r2 * 256 + tid;
      int row = idx >> 3, k8 = idx & 7;
      gl_lds16(Bsrc + (size_t)row * 1024 + kt * 128 + k8 * 16, lds + 16384 + ((idx >> 6) << 10));
    }
    __syncthreads();
    #pragma unroll
    for (int kk = 0; kk < 2; ++kk){
      short8 af[4], bf[4];
      int kb = kk * 64 + q * 16;
      #pragma unroll
      for (int mf = 0; mf < 4; ++mf){
        int row = wm * 64 + mf * 16 + c;
        af[mf] = *(const short8*)(lds + row * 128 + (kb ^ ((row & 7) << 4)));
      }
      #pragma unroll
      for (int nf = 0; nf < 4; ++nf){
        int row = wn * 64 + nf * 16 + c;
        bf[nf] = *(const short8*)(lds + 16384 + row * 128 + (kb ^ ((row & 7) << 4)));
      }
      #pragma unroll
      for (int mf = 0; mf < 4; ++mf)
        #pragma unroll
        for (int nf = 0; nf < 4; ++nf)
          acc[mf][nf] = __builtin_amdgcn_mfma_f32_16x16x32_bf16(af[mf], bf[nf], acc[mf][nf], 0, 0, 0);
    }
    __syncthreads();
  }
  // epilogue: add bias, cvt bf16, store TRANSPOSED [s][n][b], 8B per (mf,nf)
  int sidx = mt * 2 + wm;             // row>>6 (mf*16+q*4+j <= 63)
  #pragma unroll
  for (int nf = 0; nf < 4; ++nf){
    int n = n0 + wn * 64 + nf * 16 + c;
    float bv = bi[n];
    #pragma unroll
    for (int mf = 0; mf < 4; ++mf){
      int b0 = mf * 16 + q * 4;       // batch of j=0
      u32 w0 = (u32)f2bf(acc[mf][nf][0] + bv) | ((u32)f2bf(acc[mf][nf][1] + bv) << 16);
      u32 w1 = (u32)f2bf(acc[mf][nf][2] + bv) | ((u32)f2bf(acc[mf][nf][3] + bv) << 16);
      uint2 o; o.x = w0; o.y = w1;
      *(uint2*)(xg + ((size_t)sidx * NH + n) * NB + b0) = o;
    }
  }
}

// ---------------- persistent recurrent kernel ----------------
// Round-0's PROVEN protocol verbatim (per-WG MALL flags, per-lane 16-line
// vector poll, WG transpose tile with TBAA-safe barriers). Two isolated
// micro-reorders only:
//  (1) out stores AFTER the flag post -> the publish vmcnt(0) drain no
//      longer waits on out-store HBM acks;
//  (2) x loads AFTER the poll -> the poll's implicit vmcnt(0) waits only on
//      the poll load itself (pure MALL RT per sample); x HBM latency hides
//      under staging + LDS + MFMA before combine consumes it.
__global__ __launch_bounds__(256, 1) void GRU_rec(const u16* __restrict__ WH,
    const u16* __restrict__ xr, const u16* __restrict__ xz, const u16* __restrict__ xn,
    const float* __restrict__ bhr, const float* __restrict__ bhz, const float* __restrict__ bhn,
    const float* __restrict__ h0, u16* __restrict__ hImg, u32* __restrict__ flags,
    float* __restrict__ out){
  __shared__ __align__(16) char hl[34816];      // [16 rows][2048B] swizzled + 2KB tile @32768
  int tid = threadIdx.x;
  int l = tid & 63, w = tid >> 6;
  int wg = blockIdx.x;
  int bg = wg >> 4, fg = wg & 15;
  int c = l & 15, q = l >> 4;

  // weights -> registers: bw[gate][kc]  (384 regs, AGPR-backed)
  short8 bw[3][32];
  {
    const short8* base = (const short8*)WH;
    int ft = fg * 4 + w;
    #pragma unroll
    for (int g = 0; g < 3; ++g)
      #pragma unroll
      for (int kc = 0; kc < 32; ++kc)
        bw[g][kc] = base[(size_t)((g * 64 + ft) * 32 + kc) * 64 + l];
  }

  int frow = fg * 64 + w * 16 + c;              // this lane's feature
  int brow = bg * 16 + q * 4;                   // this lane's first batch row
  float vbhr = bhr[frow], vbhz = bhz[frow], vbhn = bhn[frow];

  float hprev[4];
  #pragma unroll
  for (int j = 0; j < 4; ++j) hprev[j] = h0[(size_t)(brow + j) * NH + frow];

  char* hbytes = (char*)hImg;
  u32* myflag = flags + wg * 16;
  const u32* pollp = flags + (size_t)(bg * 16 + (l & 15)) * 16;
  int r = tid >> 4, ci = tid & 15;              // staging coords

  for (int s = 0; s < NS; ++s){
    // ---- poll FIRST, with no other VMEM in flight: each sample's implicit
    // vmcnt(0) covers only the poll load itself (one MALL RT) ----
    if (s > 0){
      for (int it = 0; it < (1 << 20); ++it){   // bounded: fail-fast, never hang
        u32 v = __hip_atomic_load(pollp, __ATOMIC_RELAXED, __HIP_MEMORY_SCOPE_AGENT);
        if (__all((int)(v >= (u32)s))) break;
      }
      __builtin_amdgcn_sched_barrier(0);
      asm volatile("" ::: "memory");
    }
    // x loads issued AFTER the poll: ~900cy HBM latency hides under
    // staging + LDS + MFMA; consumed only in combine
    u64 xrv, xzv, xnv;
    {
      size_t xo = ((size_t)s * NH + frow) * NB + brow;
      xrv = *(const u64*)(xr + xo);
      xzv = *(const u64*)(xz + xo);
      xnv = *(const u64*)(xn + xo);
    }
    // stage h slice (rows bg*16..+16 of buffer s&1) via MALL-coherent loads
    {
      const u64* hsrc = (const u64*)(hbytes + (size_t)(s & 1) * 131072)
                        + (size_t)(bg * 16 + r) * 256 + ci;
      u64 hv[16];
      #pragma unroll
      for (int e = 0; e < 16; ++e) hv[e] = ald8(hsrc + e * 16);
      char* dst = hl + r * 2048;
      #pragma unroll
      for (int e = 0; e < 16; ++e)
        *(u64*)(dst + ((e * 128 + ci * 8) ^ ((r & 7) << 4))) = hv[e];
    }
    __syncthreads();

    // MFMA: acc[b16][f16] per gate, K=1024, even/odd chains
    f32x4 ar0 = (f32x4)0.0f, ar1 = (f32x4)0.0f;
    f32x4 az0 = (f32x4)0.0f, az1 = (f32x4)0.0f;
    f32x4 an0 = (f32x4)0.0f, an1 = (f32x4)0.0f;
    #pragma unroll
    for (int kc = 0; kc < 32; kc += 2){
      short8 a0 = *(const short8*)(hl + c * 2048 + ((kc * 64 + q * 16) ^ ((c & 7) << 4)));
      short8 a1 = *(const short8*)(hl + c * 2048 + (((kc + 1) * 64 + q * 16) ^ ((c & 7) << 4)));
      ar0 = __builtin_amdgcn_mfma_f32_16x16x32_bf16(a0, bw[0][kc], ar0, 0, 0, 0);
      az0 = __builtin_amdgcn_mfma_f32_16x16x32_bf16(a0, bw[1][kc], az0, 0, 0, 0);
      an0 = __builtin_amdgcn_mfma_f32_16x16x32_bf16(a0, bw[2][kc], an0, 0, 0, 0);
      ar1 = __builtin_amdgcn_mfma_f32_16x16x32_bf16(a1, bw[0][kc + 1], ar1, 0, 0, 0);
      az1 = __builtin_amdgcn_mfma_f32_16x16x32_bf16(a1, bw[1][kc + 1], az1, 0, 0, 0);
      an1 = __builtin_amdgcn_mfma_f32_16x16x32_bf16(a1, bw[2][kc + 1], an1, 0, 0, 0);
    }
    f32x4 ar = ar0 + ar1, az = az0 + az1, an = an0 + an1;

    // combine; h state carried in f32 regs; write LDS transpose tile
    float hn4[4];
    #pragma unroll
    for (int j = 0; j < 4; ++j){
      float rv = sigm(ar[j] + bf2f((u16)(xrv >> (16 * j))) + vbhr);
      float zv = sigm(az[j] + bf2f((u16)(xzv >> (16 * j))) + vbhz);
      float nv = tanhf_(bf2f((u16)(xnv >> (16 * j))) + rv * (an[j] + vbhn));
      float hn = (1.0f - zv) * nv + zv * hprev[j];
      hprev[j] = hn;
      hn4[j] = hn;
      *(u16*)(hl + 32768 + (q * 4 + j) * 128 + (w * 16 + c) * 2) = f2bf(hn);
    }
    __syncthreads();   // barrier separates u16 tile writes from u64 reads (TBAA-safe)
    // publish h tile: one 8B MALL store per thread, then ack-drain, then flag
    {
      u64 tv = *(const u64*)(hl + 32768 + r * 128 + ci * 8);
      u64* hdst = (u64*)(hbytes + (size_t)((s + 1) & 1) * 131072)
                  + (size_t)(bg * 16 + r) * 256 + fg * 16 + ci;
      ast8(hdst, tv);
    }
    asm volatile("s_waitcnt vmcnt(0)" ::: "memory");
    __syncthreads();
    if (tid == 0)
      __hip_atomic_store(myflag, (u32)(s + 1), __ATOMIC_RELAXED, __HIP_MEMORY_SCOPE_AGENT);
    // out stores AFTER the flag post: off the producer->consumer signal path;
    // their HBM acks retire during the next step's poll/staging window
    #pragma unroll
    for (int j = 0; j < 4; ++j)
      out[((size_t)(brow + j) * NS + s) * NH + frow] = hn4[j];
  }
  // final hidden state
  #pragma unroll
  for (int j = 0; j < 4; ++j)
    out[(size_t)NB * NS * NH + (size_t)(brow + j) * NH + frow] = hprev[j];
}

// ---------------- launcher (round-0 order) ----------------
extern "C" void kernel_launch(void* const* d_in, const int* in_sizes, int n_in,
                              void* d_out, int out_size, void* d_ws, size_t ws_size,
                              hipStream_t stream){
  const float* inputs = (const float*)d_in[0];
  const float* hidden = (const float*)d_in[1];
  const float* w_ir = (const float*)d_in[2];
  const float* w_iz = (const float*)d_in[3];
  const float* w_in = (const float*)d_in[4];
  const float* b_ir = (const float*)d_in[5];
  const float* b_iz = (const float*)d_in[6];
  const float* b_in = (const float*)d_in[7];
  const float* w_hr = (const float*)d_in[8];
  const float* w_hz = (const float*)d_in[9];
  const float* w_hn = (const float*)d_in[10];
  const float* b_hr = (const float*)d_in[11];
  const float* b_hz = (const float*)d_in[12];
  const float* b_hn = (const float*)d_in[13];

  char* ws = (char*)d_ws;
  u16* AT = (u16*)(ws + OFF_AT);
  u16* WI = (u16*)(ws + OFF_WI);
  u16* WH = (u16*)(ws + OFF_WH);
  u16* XR = (u16*)(ws + OFF_XR);
  u16* XZ = (u16*)(ws + OFF_XZ);
  u16* XN = (u16*)(ws + OFF_XN);
  u16* HIMG = (u16*)(ws + OFF_H);
  u32* FLAGS = (u32*)(ws + OFF_FLAGS);
  float* out = (float*)d_out;

  GRU_prep_at<<<dim3(8192), dim3(256), 0, stream>>>(inputs, AT);
  GRU_prep_wi<<<dim3(768), dim3(256), 0, stream>>>(w_ir, w_iz, w_in, WI);
  GRU_prep_wh<<<dim3(1536), dim3(256), 0, stream>>>(w_hr, w_hz, w_hn, WH);
  GRU_init_h<<<dim3(32), dim3(256), 0, stream>>>(hidden, HIMG, FLAGS);
  GRU_xproj<<<dim3(256, 8, 3), dim3(256), 0, stream>>>(AT, WI, b_ir, b_iz, b_in, XR, XZ, XN);
  GRU_rec<<<dim3(64), dim3(256), 0, stream>>>(WH, XR, XZ, XN, b_hr, b_hz, b_hn,
                                              hidden, HIMG, FLAGS, out);
}